// Round 10
// baseline (11830.943 us; speedup 1.0000x reference)
//
#include <hip/hip_runtime.h>
#include <hip/hip_bf16.h>

// Problem constants (B,T,D,L) = (16, 4096, 256, 512)
#define RNN_B 16
#define RNN_T 4096
#define RNN_D 256
#define RNN_L 512

typedef __fp16   fp16x2 __attribute__((ext_vector_type(2)));  // builtin-compatible
typedef _Float16 f16x8  __attribute__((ext_vector_type(8)));  // MFMA fragment
typedef float    f32x4  __attribute__((ext_vector_type(4)));

__device__ __forceinline__ unsigned pk2(float a, float b) {
    auto h = __builtin_amdgcn_cvt_pkrtz(a, b);   // __fp16 ext_vector(2)
    return __builtin_bit_cast(unsigned, h);
}

__device__ __forceinline__ uint4 pk4(float4 a, float4 b) {
    uint4 u;
    u.x = pk2(a.x, a.y); u.y = pk2(a.z, a.w);
    u.z = pk2(b.x, b.y); u.w = pk2(b.z, b.w);
    return u;
}

__device__ __forceinline__ float dot2u(unsigned wa, unsigned hb, float c) {
#if defined(__has_builtin) && __has_builtin(__builtin_amdgcn_fdot2)
    return __builtin_amdgcn_fdot2(__builtin_bit_cast(fp16x2, wa),
                                  __builtin_bit_cast(fp16x2, hb), c, false);
#else
    fp16x2 a = __builtin_bit_cast(fp16x2, wa), b = __builtin_bit_cast(fp16x2, hb);
    return c + (float)a[0] * (float)b[0] + (float)a[1] * (float)b[1];
#endif
}

// ---------------------------------------------------------------------------
// K1: Z[t,b,l] = sum_k x[b,t,k] * Wi[l,k] + bm[l] (f32 into hidden region).
// ---------------------------------------------------------------------------
__global__ __launch_bounds__(256) void proj_kernel(
        const float* __restrict__ x, const float* __restrict__ Wi,
        const float* __restrict__ bm, float* __restrict__ Zout) {
    __shared__ __align__(16) _Float16 As[64 * 40];
    __shared__ __align__(16) _Float16 Bs[64 * 40];

    const int bid = blockIdx.x;
    const int mt = bid >> 3, nt = bid & 7;
    const int mBase = mt * 64, nBase = nt * 64;
    const int tid = threadIdx.x;
    const int w = tid >> 6, l = tid & 63;

    const int srow = tid >> 2, skc = (tid & 3) * 8;
    const int m = mBase + srow;
    const int bb = m & 15, tt = m >> 4;
    const float* ax = x + ((size_t)bb * RNN_T + tt) * RNN_D + skc;
    const float* bw = Wi + (size_t)(nBase + srow) * RNN_D + skc;

    f32x4 acc[4] = {};

#pragma unroll 1
    for (int k0 = 0; k0 < RNN_D; k0 += 32) {
        __syncthreads();
        float4 a0 = *(const float4*)(ax + k0);
        float4 a1 = *(const float4*)(ax + k0 + 4);
        float4 b0 = *(const float4*)(bw + k0);
        float4 b1 = *(const float4*)(bw + k0 + 4);
        uint4 ua = {pk2(a0.x, a0.y), pk2(a0.z, a0.w), pk2(a1.x, a1.y), pk2(a1.z, a1.w)};
        uint4 ub = {pk2(b0.x, b0.y), pk2(b0.z, b0.w), pk2(b1.x, b1.y), pk2(b1.z, b1.w)};
        *(uint4*)(As + srow * 40 + skc) = ua;
        *(uint4*)(Bs + srow * 40 + skc) = ub;
        __syncthreads();

        f16x8 af = *(const f16x8*)(As + (w * 16 + (l & 15)) * 40 + (l >> 4) * 8);
#pragma unroll
        for (int n = 0; n < 4; ++n) {
            f16x8 bf = *(const f16x8*)(Bs + (n * 16 + (l & 15)) * 40 + (l >> 4) * 8);
            acc[n] = __builtin_amdgcn_mfma_f32_16x16x32_f16(af, bf, acc[n], 0, 0, 0);
        }
    }

    const int colL = l & 15, rg = l >> 4;
#pragma unroll
    for (int n = 0; n < 4; ++n) {
        const int col = nBase + n * 16 + colL;
        const float bias = bm[col];
#pragma unroll
        for (int q = 0; q < 4; ++q) {
            const int row = mBase + w * 16 + rg * 4 + q;
            Zout[(size_t)row * RNN_L + col] = acc[n][q] + bias;
        }
    }
}

// ---------------------------------------------------------------------------
// Kpack: pre-pack the STREAMED portion of Wm (channels c=5,6,7 of each lane's
// 8-channel set) to f16-pairs in the out_o scratch region. Layout:
// out[p*512 + tid], p = (c-5)*8 + q; content = Wm[8*l + c][64*w + 8q .. +8)
// where w = tid>>6, l = tid&63. In-loop reads are 1KB-contiguous per wave.
// ---------------------------------------------------------------------------
__global__ __launch_bounds__(512) void pack_kernel(
        const float* __restrict__ Wm, uint4* __restrict__ out) {
    const int p = blockIdx.x;            // 0..23
    const int tid = threadIdx.x;         // 0..511
    const int c = 5 + (p >> 3), q = p & 7;
    const int w = tid >> 6, l = tid & 63;
    const int row = 8 * l + c;
    const float4* r4 = (const float4*)(Wm + (size_t)row * RNN_L);
    const int kf4 = 16 * w + 2 * q;
    out[p * 512 + tid] = pk4(r4[kf4], r4[kf4 + 1]);
}

// ---------------------------------------------------------------------------
// K2: sequential scan, R8 k-split shape, weight-flow rebalanced onto VMEM.
// R3-R9 forensics: step time (~3400 cyc) invariant because BOTH the LDS pipe
// (weights + h-fanout, ~3400 cyc) and VALU (dots 1024 + AGPR-park move tax
// ~800) saturate at ~the same envelope. VMEM/L2 is idle -> stream 3 of the
// 8 channels' weights from an f16-prepacked L2-resident copy every step
// (192KB/step/CU, issued at step top, consumed after VGPR-channel dots).
// LDS now holds ONLY part[] + hbuf[] (19 KB static, no dynamic LDS).
//  * wave w owns k in [64w,64w+64); lane computes partials for 8 channels
//    j = 8*(tid&63) + c; ch 0-4 weights in named VGPRs, ch 5-7 streamed.
//  * cross-wave reduce via padded part[8][8][65]; 2 barriers/step.
//  * z prefetched 1 step ahead; h double-buffered f16x2 in LDS.
// ---------------------------------------------------------------------------
#define DECL8(c) uint4 W##c##_0, W##c##_1, W##c##_2, W##c##_3, \
                       W##c##_4, W##c##_5, W##c##_6, W##c##_7
#define LOAD8(c) do { \
    const float4* p_ = (const float4*)(Wm + (size_t)(8 * l + (c)) * RNN_L + 64 * w); \
    W##c##_0 = pk4(p_[0], p_[1]);   W##c##_1 = pk4(p_[2], p_[3]); \
    W##c##_2 = pk4(p_[4], p_[5]);   W##c##_3 = pk4(p_[6], p_[7]); \
    W##c##_4 = pk4(p_[8], p_[9]);   W##c##_5 = pk4(p_[10], p_[11]); \
    W##c##_6 = pk4(p_[12], p_[13]); W##c##_7 = pk4(p_[14], p_[15]); } while (0)
#define DOT_U4(W, H, A) do { A = dot2u((W).x, (H).x, A); A = dot2u((W).y, (H).y, A); \
                             A = dot2u((W).z, (H).z, A); A = dot2u((W).w, (H).w, A); } while (0)
#define DOTH1(c) do { DOT_U4(W##c##_0, hh0, acc##c); DOT_U4(W##c##_1, hh1, acc##c); \
                      DOT_U4(W##c##_2, hh2, acc##c); DOT_U4(W##c##_3, hh3, acc##c); } while (0)
#define DOTH2(c) do { DOT_U4(W##c##_4, hh4, acc##c); DOT_U4(W##c##_5, hh5, acc##c); \
                      DOT_U4(W##c##_6, hh6, acc##c); DOT_U4(W##c##_7, hh7, acc##c); } while (0)

__global__ __launch_bounds__(512) void rnn_scan(
        const float* __restrict__ Wm, float* __restrict__ out_h,
        const uint4* __restrict__ swS /* 24*512 uint4 packed stream weights */) {
    __shared__ __align__(16) float part[8 * 8 * 65];   // 16640 B, padded
    __shared__ unsigned hbuf[2 * 256];                 // 2048 B

    const int b = blockIdx.x;
    const int tid = threadIdx.x;
    const int w = tid >> 6, l = tid & 63;

    // ---- prologue: ch 0-4 weights -> named VGPRs ----
    DECL8(0); DECL8(1); DECL8(2); DECL8(3); DECL8(4);
    LOAD8(0); LOAD8(1); LOAD8(2); LOAD8(3); LOAD8(4);
    hbuf[tid] = 0;          // 512 u32 = both h buffers (h0 = 0)
    __syncthreads();

    float* zh = out_h + (size_t)b * RNN_L + tid;       // Z in, h out (f32)
    const uint4* sw = swS + tid;                       // stream base, this lane
    float z = zh[0];

#pragma unroll 1
    for (int t = 0; t < RNN_T; ++t) {
        const int cur = t & 1, nxt = cur ^ 1;
        const int tn = (t < RNN_T - 1) ? t + 1 : t;
        const float znext = zh[(size_t)tn * (RNN_B * RNN_L)];

        // stream group 1: ch5/6/7, k-quarters q0..3 (issued before dots)
        uint4 s50 = sw[(0 * 8 + 0) * 512], s51 = sw[(0 * 8 + 1) * 512];
        uint4 s52 = sw[(0 * 8 + 2) * 512], s53 = sw[(0 * 8 + 3) * 512];
        uint4 s60 = sw[(1 * 8 + 0) * 512], s61 = sw[(1 * 8 + 1) * 512];
        uint4 s62 = sw[(1 * 8 + 2) * 512], s63 = sw[(1 * 8 + 3) * 512];
        uint4 s70 = sw[(2 * 8 + 0) * 512], s71 = sw[(2 * 8 + 1) * 512];
        uint4 s72 = sw[(2 * 8 + 2) * 512], s73 = sw[(2 * 8 + 3) * 512];

        const uint4* hb4 = (const uint4*)(hbuf + cur * 256) + w * 8;  // uniform
        float acc0 = 0.f, acc1 = 0.f, acc2 = 0.f, acc3 = 0.f;
        float acc4 = 0.f, acc5 = 0.f, acc6 = 0.f, acc7 = 0.f;
        {
            uint4 hh0 = hb4[0], hh1 = hb4[1], hh2 = hb4[2], hh3 = hb4[3];
            DOTH1(0); DOTH1(1); DOTH1(2); DOTH1(3); DOTH1(4);   // VGPR chans
            // stream group 2 issued under the dots above
            uint4 s54 = sw[(0 * 8 + 4) * 512], s55 = sw[(0 * 8 + 5) * 512];
            uint4 s56 = sw[(0 * 8 + 6) * 512], s57 = sw[(0 * 8 + 7) * 512];
            uint4 s64 = sw[(1 * 8 + 4) * 512], s65 = sw[(1 * 8 + 5) * 512];
            uint4 s66 = sw[(1 * 8 + 6) * 512], s67 = sw[(1 * 8 + 7) * 512];
            uint4 s74 = sw[(2 * 8 + 4) * 512], s75 = sw[(2 * 8 + 5) * 512];
            uint4 s76 = sw[(2 * 8 + 6) * 512], s77 = sw[(2 * 8 + 7) * 512];
            // streamed dots, group 1
            DOT_U4(s50, hh0, acc5); DOT_U4(s51, hh1, acc5);
            DOT_U4(s52, hh2, acc5); DOT_U4(s53, hh3, acc5);
            DOT_U4(s60, hh0, acc6); DOT_U4(s61, hh1, acc6);
            DOT_U4(s62, hh2, acc6); DOT_U4(s63, hh3, acc6);
            DOT_U4(s70, hh0, acc7); DOT_U4(s71, hh1, acc7);
            DOT_U4(s72, hh2, acc7); DOT_U4(s73, hh3, acc7);

            uint4 hh4 = hb4[4], hh5 = hb4[5], hh6 = hb4[6], hh7 = hb4[7];
            DOTH2(0); DOTH2(1); DOTH2(2); DOTH2(3); DOTH2(4);
            // streamed dots, group 2
            DOT_U4(s54, hh4, acc5); DOT_U4(s55, hh5, acc5);
            DOT_U4(s56, hh6, acc5); DOT_U4(s57, hh7, acc5);
            DOT_U4(s64, hh4, acc6); DOT_U4(s65, hh5, acc6);
            DOT_U4(s66, hh6, acc6); DOT_U4(s67, hh7, acc6);
            DOT_U4(s74, hh4, acc7); DOT_U4(s75, hh5, acc7);
            DOT_U4(s76, hh6, acc7); DOT_U4(s77, hh7, acc7);
        }

        // part[c][w][l], inner dim padded to 65 (conflict-benign)
        part[(0 * 8 + w) * 65 + l] = acc0;
        part[(1 * 8 + w) * 65 + l] = acc1;
        part[(2 * 8 + w) * 65 + l] = acc2;
        part[(3 * 8 + w) * 65 + l] = acc3;
        part[(4 * 8 + w) * 65 + l] = acc4;
        part[(5 * 8 + w) * 65 + l] = acc5;
        part[(6 * 8 + w) * 65 + l] = acc6;
        part[(7 * 8 + w) * 65 + l] = acc7;

        __syncthreads();   // B1: partials visible

        // thread tid reduces channel j = tid
        const int c2 = tid & 7, l2 = tid >> 3;
        float s = 0.f;
#pragma unroll
        for (int w2 = 0; w2 < 8; ++w2) s += part[(c2 * 8 + w2) * 65 + l2];

        const float pre = z + s;
        const float hn = 1.f / (1.f + __expf(-pre));

        const float hnb = __shfl_down(hn, 1);
        if (!(tid & 1)) hbuf[nxt * 256 + (tid >> 1)] = pk2(hn, hnb);

        __syncthreads();   // B2: next h buffer ready; partials reusable

        zh[(size_t)t * (RNN_B * RNN_L)] = hn;   // after barrier, never waited on
        z = znext;
    }
}

// ---------------------------------------------------------------------------
// K3: o[t,b] = sum_j Wo[j] * h[t,b,j]. Memory-bound re-read of h (~134 MB).
// Overwrites the out_o region (which held the packed stream weights).
// ---------------------------------------------------------------------------
__global__ __launch_bounds__(256) void out_proj(
        const float* __restrict__ Wo, const float* __restrict__ h,
        float* __restrict__ o) {
    const int l = threadIdx.x & 63;
    const int r = blockIdx.x * 4 + (threadIdx.x >> 6);   // r = t*B + b
    const float4* hp = (const float4*)(h + (size_t)r * RNN_L);
    const float4* wp = (const float4*)Wo;
    float4 a0 = hp[l * 2], a1 = hp[l * 2 + 1];
    float4 b0 = wp[l * 2], b1 = wp[l * 2 + 1];
    float s = a0.x * b0.x + a0.y * b0.y + a0.z * b0.z + a0.w * b0.w
            + a1.x * b1.x + a1.y * b1.y + a1.z * b1.z + a1.w * b1.w;
#pragma unroll
    for (int off = 1; off < 64; off <<= 1) s += __shfl_xor(s, off);
    if (l == 0) o[r] = s;
}

// ---------------------------------------------------------------------------
extern "C" void kernel_launch(void* const* d_in, const int* in_sizes, int n_in,
                              void* d_out, int out_size, void* d_ws, size_t ws_size,
                              hipStream_t stream) {
    const float* x  = (const float*)d_in[0];   // [16,4096,256]
    const float* Wi = (const float*)d_in[1];   // [512,256]
    const float* Wm = (const float*)d_in[2];   // [512,512]
    const float* bm = (const float*)d_in[3];   // [512]
    const float* Wo = (const float*)d_in[4];   // [1,512]

    float* out_o = (float*)d_out;                 // [T*B] floats (256 KB)
    float* out_h = out_o + (RNN_T * RNN_B);       // [T*B*L] floats

    // K1: Z = x @ Wi^T + bm  -> hidden region (scratch, overwritten by K2)
    proj_kernel<<<dim3((RNN_T * RNN_B / 64) * (RNN_L / 64)), dim3(256), 0, stream>>>(
        x, Wi, bm, out_h);

    // Kpack: f16-prepack streamed weight channels into out_o scratch (192 KB)
    pack_kernel<<<dim3(24), dim3(512), 0, stream>>>(Wm, (uint4*)out_o);

    // K2: sequential recurrence (16 WGs, static 19 KB LDS)
    rnn_scan<<<dim3(RNN_B), dim3(512), 0, stream>>>(Wm, out_h, (const uint4*)out_o);

    // K3: o = h . Wo (overwrites the scratch region with real outputs)
    out_proj<<<dim3(RNN_T * RNN_B / 4), dim3(256), 0, stream>>>(Wo, out_h, out_o);
}